// Round 10
// baseline (534.753 us; speedup 1.0000x reference)
//
#include <hip/hip_runtime.h>
#include <cstddef>

#define Bn 256
#define Hd 128
#define Nd 2048
#define K3 384     // W row stride (3H)
#define BPC 8      // b-values per persistent block; grid = 16 ntiles x 32 chunks

typedef _Float16 half8 __attribute__((ext_vector_type(8)));
typedef float    float4v __attribute__((ext_vector_type(4)));

#define SFENCE() __builtin_amdgcn_sched_barrier(0)

__device__ __forceinline__ float fast_tanh(float x) {
    // tanh(x) = 1 - 2/(exp(2x)+1); saturates correctly at +/-inf
    return 1.0f - __fdividef(2.0f, __expf(2.0f * x) + 1.0f);
}

// ---------------------------------------------------------------------------
// prep 1: Wf[h][k] = fp16(W[h][k]) for k<256  (static+dynamic columns)
__global__ void prep_w16(const float* __restrict__ W, _Float16* __restrict__ Wf) {
    int idx = blockIdx.x * 256 + threadIdx.x;   // 0..32767
    int h = idx >> 8, k = idx & 255;
    Wf[idx] = (_Float16)W[h * K3 + k];
}

// prep 2: c[b][h] = sum_k W[h][256+k] * dec[b][k]  (decoder term, fp32 exact)
__global__ void prep_c(const float* __restrict__ W, const float* __restrict__ dec,
                       float* __restrict__ cb) {
    __shared__ float dl[Hd];
    int b = blockIdx.x;
    int h = threadIdx.x;       // 128 threads
    dl[h] = dec[b * Hd + h];
    __syncthreads();
    float acc = 0.f;
    #pragma unroll 8
    for (int k = 0; k < Hd; ++k)
        acc = fmaf(W[h * K3 + 256 + k], dl[k], acc);
    cb[b * Hd + h] = acc;
}

// ---------------------------------------------------------------------------
// Main: R9 structure made PERSISTENT so BOTH staging halves overlap MFMA.
// R9 post-mortem: hiding dyn loads under kt0-3 won ~40us (556->513 total);
// static stage remained serial at block start. Here each block loops over
// BPC=8 b-values: phase C hides the NEXT iteration's static stage under
// kt4-7 (dyn MFMA) symmetrically to phase B. LDS halves are disjoint chunk
// ranges (static 0..15, dyn 16..31) so tile-(i+1) static writes proceed
// while tile-i dyn chunks are read. 2 barriers/iter (read/write sets
// checked): sync2 (dyn writes -> kt4-7 reads), sync3 (static+red writes ->
// next phase B + red reads). MFMA order kt0..7 unchanged => bit-identical
// numerics (absmax 7.63e-6). cbp prefetched one iter ahead.
//
// block = (n-tile, b-chunk): 256 thr = 4 waves, 2 blocks/CU (66 KB LDS).
// Wave w: h in [32w,32w+32) (2 M-tiles), all 128 n (8 N-tiles), acc[2][8].
// A-frags resident from L2-hot Wf. x staged [n][k] fp16, 16B-chunk XOR
// swizzle p = ck ^ ((n>>1)&7).
__global__ __launch_bounds__(256, 2)
void score_kernel(const float* __restrict__ shp, const float* __restrict__ dhp,
                  const _Float16* __restrict__ Wf, const float* __restrict__ cbp,
                  const float* __restrict__ v, float* __restrict__ out) {
    __shared__ __align__(16) _Float16 xl[128 * 256];   // 64 KB, swizzled
    __shared__ float red[4 * 128];

    const int tid  = threadIdx.x;
    const int w    = __builtin_amdgcn_readfirstlane(tid >> 6);  // wave id (SGPR)
    const int lane = tid & 63;
    const int qd   = lane >> 4;       // quad 0..3
    const int ln   = lane & 15;
    const int bid  = blockIdx.x;
    const int n0   = (bid & 15) * 128;
    const int b0   = (bid >> 4) * BPC;
    const int h0   = w * 32;

    // ---- A fragments (W) -> registers. A[m=lane&15][k=quad*8+j].
    half8 Af[2][8];
    #pragma unroll
    for (int Mt = 0; Mt < 2; ++Mt) {
        const _Float16* wp = Wf + ((h0 + Mt * 16 + ln) << 8) + qd * 8;
        #pragma unroll
        for (int kt = 0; kt < 8; ++kt)
            Af[Mt][kt] = *reinterpret_cast<const half8*>(wp + kt * 32);
    }
    const float4v v0 = *reinterpret_cast<const float4v*>(v + h0 + qd * 4);
    const float4v v1 = *reinterpret_cast<const float4v*>(v + h0 + 16 + qd * 4);

    // ---- staging constants: lane covers n1, n1+1 for an 8-row k band per i
    const int n1  = 2 * lane;        // even row
    const int swz = lane & 7;        // ((n1>>1)&7) == ((n1+1)>>1)&7
    const int swr = (ln >> 1) & 7;
    const size_t bstr = (size_t)Hd * Nd;
    const float* sbase = shp + (size_t)b0 * bstr + n0 + n1;
    const float* dbase = dhp + (size_t)b0 * bstr + n0 + n1;

    // ---- prologue: stage static half of b0 (logical chunks 0..15)
    #pragma unroll
    for (int i = 0; i < 4; ++i) {
        const int kl = i * 32 + w * 8;          // wave-uniform, 0..120
        float2 xv[8];
        #pragma unroll
        for (int j = 0; j < 8; ++j)
            xv[j] = *reinterpret_cast<const float2*>(sbase + (size_t)(kl + j) * Nd);
        half8 e0, e1;
        #pragma unroll
        for (int j = 0; j < 8; ++j) {
            e0[j] = (_Float16)xv[j].x;
            e1[j] = (_Float16)xv[j].y;
        }
        const int p = (kl >> 3) ^ swz;
        *reinterpret_cast<half8*>(&xl[n1 * 256 + p * 8])       = e0;
        *reinterpret_cast<half8*>(&xl[(n1 + 1) * 256 + p * 8]) = e1;
    }
    float4v c0 = *reinterpret_cast<const float4v*>(cbp + (size_t)b0 * Hd + h0 + qd * 4);
    float4v c1 = *reinterpret_cast<const float4v*>(cbp + (size_t)b0 * Hd + h0 + 16 + qd * 4);
    __syncthreads();

    #pragma unroll 1
    for (int it = 0; it < BPC; ++it) {
        // ---- acc init with decoder term (c0/c1 prefetched)
        float4v acc[2][8];
        #pragma unroll
        for (int Nt = 0; Nt < 8; ++Nt) { acc[0][Nt] = c0; acc[1][Nt] = c1; }

        const float* dsrc = dbase + (size_t)it * bstr;

        // ---- phase B: {issue dyn-it loads | MFMA kt0-3 (static) | write dyn}
        #pragma unroll
        for (int hp = 0; hp < 2; ++hp) {
            float2 yv[2][8];
            #pragma unroll
            for (int i2 = 0; i2 < 2; ++i2) {
                const int kl = (2 * hp + i2) * 32 + w * 8;
                #pragma unroll
                for (int j = 0; j < 8; ++j)
                    yv[i2][j] = *reinterpret_cast<const float2*>(dsrc + (size_t)(kl + j) * Nd);
            }
            SFENCE();   // pin load issue above the MFMA cluster
            #pragma unroll
            for (int kt = 2 * hp; kt < 2 * hp + 2; ++kt) {
                half8 Bf[8];
                const int ckb = kt * 4 + qd;
                #pragma unroll
                for (int Nt = 0; Nt < 8; ++Nt) {
                    const int row = Nt * 16 + ln;
                    Bf[Nt] = *reinterpret_cast<const half8*>(&xl[row * 256 + ((ckb ^ swr) << 3)]);
                }
                #pragma unroll
                for (int Nt = 0; Nt < 8; ++Nt) {
                    acc[0][Nt] = __builtin_amdgcn_mfma_f32_16x16x32_f16(Af[0][kt], Bf[Nt], acc[0][Nt], 0, 0, 0);
                    acc[1][Nt] = __builtin_amdgcn_mfma_f32_16x16x32_f16(Af[1][kt], Bf[Nt], acc[1][Nt], 0, 0, 0);
                }
            }
            SFENCE();
            #pragma unroll
            for (int i2 = 0; i2 < 2; ++i2) {
                const int kl = (2 * hp + i2) * 32 + w * 8;
                half8 e0, e1;
                #pragma unroll
                for (int j = 0; j < 8; ++j) {
                    e0[j] = (_Float16)yv[i2][j].x;
                    e1[j] = (_Float16)yv[i2][j].y;
                }
                const int p = ((128 + kl) >> 3) ^ swz;
                *reinterpret_cast<half8*>(&xl[n1 * 256 + p * 8])       = e0;
                *reinterpret_cast<half8*>(&xl[(n1 + 1) * 256 + p * 8]) = e1;
            }
        }
        __syncthreads();   // sync2: dyn writes visible for kt4-7

        // ---- phase C: {issue static-(it+1) | MFMA kt4-7 (dyn) | write static}
        const bool pf = (it + 1 < BPC);
        const float* snxt = sbase + (size_t)(it + 1) * bstr;
        #pragma unroll
        for (int hp = 0; hp < 2; ++hp) {
            float2 xv[2][8];
            if (pf) {
                #pragma unroll
                for (int i2 = 0; i2 < 2; ++i2) {
                    const int kl = (2 * hp + i2) * 32 + w * 8;
                    #pragma unroll
                    for (int j = 0; j < 8; ++j)
                        xv[i2][j] = *reinterpret_cast<const float2*>(snxt + (size_t)(kl + j) * Nd);
                }
            }
            SFENCE();
            #pragma unroll
            for (int kt = 4 + 2 * hp; kt < 6 + 2 * hp; ++kt) {
                half8 Bf[8];
                const int ckb = kt * 4 + qd;
                #pragma unroll
                for (int Nt = 0; Nt < 8; ++Nt) {
                    const int row = Nt * 16 + ln;
                    Bf[Nt] = *reinterpret_cast<const half8*>(&xl[row * 256 + ((ckb ^ swr) << 3)]);
                }
                #pragma unroll
                for (int Nt = 0; Nt < 8; ++Nt) {
                    acc[0][Nt] = __builtin_amdgcn_mfma_f32_16x16x32_f16(Af[0][kt], Bf[Nt], acc[0][Nt], 0, 0, 0);
                    acc[1][Nt] = __builtin_amdgcn_mfma_f32_16x16x32_f16(Af[1][kt], Bf[Nt], acc[1][Nt], 0, 0, 0);
                }
            }
            SFENCE();
            if (pf) {
                #pragma unroll
                for (int i2 = 0; i2 < 2; ++i2) {
                    const int kl = (2 * hp + i2) * 32 + w * 8;
                    half8 e0, e1;
                    #pragma unroll
                    for (int j = 0; j < 8; ++j) {
                        e0[j] = (_Float16)xv[i2][j].x;
                        e1[j] = (_Float16)xv[i2][j].y;
                    }
                    const int p = (kl >> 3) ^ swz;
                    *reinterpret_cast<half8*>(&xl[n1 * 256 + p * 8])       = e0;
                    *reinterpret_cast<half8*>(&xl[(n1 + 1) * 256 + p * 8]) = e1;
                }
            }
        }
        // prefetch next cbp (consumed at next acc init)
        if (pf) {
            c0 = *reinterpret_cast<const float4v*>(cbp + (size_t)(b0 + it + 1) * Hd + h0 + qd * 4);
            c1 = *reinterpret_cast<const float4v*>(cbp + (size_t)(b0 + it + 1) * Hd + h0 + 16 + qd * 4);
        }

        // ---- epilogue: score[n] = sum_m v[m] * tanh(t[m][n])
        #pragma unroll
        for (int Nt = 0; Nt < 8; ++Nt) {
            float part = 0.f;
            #pragma unroll
            for (int r = 0; r < 4; ++r) {
                part = fmaf(v0[r], fast_tanh(acc[0][Nt][r]), part);
                part = fmaf(v1[r], fast_tanh(acc[1][Nt][r]), part);
            }
            part += __shfl_xor(part, 16);   // sum quads (same n)
            part += __shfl_xor(part, 32);
            if (qd == 0) red[w * 128 + Nt * 16 + ln] = part;
        }
        __syncthreads();   // sync3: static-(it+1) + red writes visible
        if (tid < 128) {
            float s = red[tid] + red[128 + tid] + red[256 + tid] + red[384 + tid];
            out[(size_t)(b0 + it) * Nd + n0 + tid] = s;
        }
    }
}

// ---------------------------------------------------------------------------
// softmax over n=2048 per b, in place. (validated round 1)
__global__ void softmax_k(float* __restrict__ out) {
    int b = blockIdx.x;
    float* row = out + (size_t)b * Nd;
    int tid = threadIdx.x;

    float loc[8];
    float mx = -3.4e38f;
    #pragma unroll
    for (int i = 0; i < 8; ++i) {
        loc[i] = row[tid + (i << 8)];
        mx = fmaxf(mx, loc[i]);
    }
    #pragma unroll
    for (int off = 32; off > 0; off >>= 1) mx = fmaxf(mx, __shfl_xor(mx, off));
    __shared__ float s4[4];
    if ((tid & 63) == 0) s4[tid >> 6] = mx;
    __syncthreads();
    mx = fmaxf(fmaxf(s4[0], s4[1]), fmaxf(s4[2], s4[3]));

    float sum = 0.f;
    #pragma unroll
    for (int i = 0; i < 8; ++i) {
        loc[i] = __expf(loc[i] - mx);
        sum += loc[i];
    }
    #pragma unroll
    for (int off = 32; off > 0; off >>= 1) sum += __shfl_xor(sum, off);
    __shared__ float s4b[4];
    if ((tid & 63) == 0) s4b[tid >> 6] = sum;
    __syncthreads();
    sum = s4b[0] + s4b[1] + s4b[2] + s4b[3];

    float inv = 1.0f / sum;
    #pragma unroll
    for (int i = 0; i < 8; ++i) row[tid + (i << 8)] = loc[i] * inv;
}

// ---------------------------------------------------------------------------
extern "C" void kernel_launch(void* const* d_in, const int* in_sizes, int n_in,
                              void* d_out, int out_size, void* d_ws, size_t ws_size,
                              hipStream_t stream) {
    const float* shp = (const float*)d_in[0];   // static_hidden [B,H,N]
    const float* dhp = (const float*)d_in[1];   // dynamic_hidden [B,H,N]
    const float* dec = (const float*)d_in[2];   // decoder_hidden [B,H]
    const float* v   = (const float*)d_in[3];   // [H]
    const float* W   = (const float*)d_in[4];   // [H, 3H]
    float* out = (float*)d_out;                 // [B,1,N]

    _Float16* Wf = (_Float16*)d_ws;             // 32768 halves = 64 KB
    float* cbp = (float*)((char*)d_ws + 65536); // 32768 floats = 128 KB

    hipLaunchKernelGGL(prep_w16, dim3(128), dim3(256), 0, stream, W, Wf);
    hipLaunchKernelGGL(prep_c,   dim3(Bn),  dim3(Hd),  0, stream, W, dec, cbp);
    hipLaunchKernelGGL(score_kernel, dim3(16 * (Bn / BPC)), dim3(256), 0, stream,
                       shp, dhp, Wf, cbp, v, out);
    hipLaunchKernelGGL(softmax_k, dim3(Bn), dim3(256), 0, stream, out);
}

// Round 12
// 515.226 us; speedup vs baseline: 1.0379x; 1.0379x over previous
//
#include <hip/hip_runtime.h>
#include <cstddef>

#define Bn 256
#define Hd 128
#define Nd 2048
#define K3 384     // W row stride (3H)

typedef _Float16 half8 __attribute__((ext_vector_type(8)));
typedef float    float4v __attribute__((ext_vector_type(4)));

#define SFENCE() __builtin_amdgcn_sched_barrier(0)

__device__ __forceinline__ float fast_tanh(float x) {
    // tanh(x) = 1 - 2/(exp(2x)+1); saturates correctly at +/-inf
    return 1.0f - __fdividef(2.0f, __expf(2.0f * x) + 1.0f);
}

// ---------------------------------------------------------------------------
// prep 1: Wf[h][k] = fp16(W[h][k]) for k<256  (static+dynamic columns)
__global__ void prep_w16(const float* __restrict__ W, _Float16* __restrict__ Wf) {
    int idx = blockIdx.x * 256 + threadIdx.x;   // 0..32767
    int h = idx >> 8, k = idx & 255;
    Wf[idx] = (_Float16)W[h * K3 + k];
}

// prep 2: c[b][h] = sum_k W[h][256+k] * dec[b][k]  (decoder term, fp32 exact)
__global__ void prep_c(const float* __restrict__ W, const float* __restrict__ dec,
                       float* __restrict__ cb) {
    __shared__ float dl[Hd];
    int b = blockIdx.x;
    int h = threadIdx.x;       // 128 threads
    dl[h] = dec[b * Hd + h];
    __syncthreads();
    float acc = 0.f;
    #pragma unroll 8
    for (int k = 0; k < Hd; ++k)
        acc = fmaf(W[h * K3 + 256 + k], dl[k], acc);
    cb[b * Hd + h] = acc;
}

// ---------------------------------------------------------------------------
// Main: R9 structure (best passing: 512.9us total), staging upgraded to
// float4 grain. R11 post-mortem: persistent variants intermittently diverge
// under graph replay (R7/R11) -- persistent branch closed; R9's
// non-persistent overlap schedule is the validated base.
//
// Staging change (only): lane mapping per 16-row burst: instruction j has
// 32 lanes (hi=0) read row kl+j and 32 lanes (hi=1) read row kl+8+j as
// contiguous 512B segments; lane (c=lane&31, hi) collects 8 contiguous k
// (one 16B chunk ck) x 4 n -> FOUR half8 swizzled LDS writes. Prologue
// 32->16 loads/lane, phase-B 16->8 per hp; 16B/lane coalescing (G13).
// LDS content, swizzle p = ck ^ ((n>>1)&7), MFMA order kt0..7, epilogue
// all IDENTICAL to R9 => bit-identical numerics (absmax 7.63e-6).
//
// block = (b, 128-n tile), 256 thr = 4 waves, 2 blocks/CU (66 KB LDS).
// Wave w: h in [32w,32w+32) (2 M-tiles), all 128 n (8 N-tiles), acc[2][8].
// Phase B hides dyn-half loads under static MFMA kt0-3 (R9-validated win).
__global__ __launch_bounds__(256, 2)
void score_kernel(const float* __restrict__ shp, const float* __restrict__ dhp,
                  const _Float16* __restrict__ Wf, const float* __restrict__ cbp,
                  const float* __restrict__ v, float* __restrict__ out) {
    __shared__ __align__(16) _Float16 xl[128 * 256];   // 64 KB, swizzled
    __shared__ float red[4 * 128];

    const int tid  = threadIdx.x;
    const int w    = __builtin_amdgcn_readfirstlane(tid >> 6);  // wave id (SGPR)
    const int lane = tid & 63;
    const int qd   = lane >> 4;       // quad 0..3
    const int ln   = lane & 15;
    const int b    = blockIdx.y;
    const int n0   = blockIdx.x * 128;
    const int h0   = w * 32;
    const int c31  = lane & 31;
    const int hi2  = lane >> 5;

    // ---- A fragments (W) -> registers. A[m=lane&15][k=quad*8+j].
    half8 Af[2][8];
    #pragma unroll
    for (int Mt = 0; Mt < 2; ++Mt) {
        const _Float16* wp = Wf + ((h0 + Mt * 16 + ln) << 8) + qd * 8;
        #pragma unroll
        for (int kt = 0; kt < 8; ++kt)
            Af[Mt][kt] = *reinterpret_cast<const half8*>(wp + kt * 32);
    }

    const size_t bofs4 = (size_t)b * (Hd * (size_t)Nd) + n0 + 4 * c31;

    // ---- prologue: stage static half (chunks 0..15), float4 grain.
    // Burst i: rows kl = 64i + 16w; lane -> rows kl+8*hi2+j (j=0..7), n=4*c31.
    {
        const float* src = shp + bofs4;
        const int kl0 = 16 * w, kl1 = 64 + 16 * w;
        float4v t0[8], t1[8];
        #pragma unroll
        for (int j = 0; j < 8; ++j)
            t0[j] = *reinterpret_cast<const float4v*>(src + (size_t)(kl0 + 8 * hi2 + j) * Nd);
        #pragma unroll
        for (int j = 0; j < 8; ++j)
            t1[j] = *reinterpret_cast<const float4v*>(src + (size_t)(kl1 + 8 * hi2 + j) * Nd);
        const int ck0 = (kl0 >> 3) + hi2;          // 2w+hi2   in 0..7
        const int ck1 = (kl1 >> 3) + hi2;          // 8+2w+hi2 in 8..15
        #pragma unroll
        for (int r = 0; r < 4; ++r) {
            const int n  = 4 * c31 + r;
            const int sw = (n >> 1) & 7;
            half8 e0, e1;
            #pragma unroll
            for (int j = 0; j < 8; ++j) {
                e0[j] = (_Float16)t0[j][r];
                e1[j] = (_Float16)t1[j][r];
            }
            *reinterpret_cast<half8*>(&xl[n * 256 + ((ck0 ^ sw) << 3)]) = e0;
            *reinterpret_cast<half8*>(&xl[n * 256 + ((ck1 ^ sw) << 3)]) = e1;
        }
    }

    // ---- acc init with decoder term (after prologue: lower reg peak)
    float4v acc[2][8];
    #pragma unroll
    for (int Mt = 0; Mt < 2; ++Mt) {
        float4v c4 = *reinterpret_cast<const float4v*>(cbp + b * Hd + h0 + Mt * 16 + qd * 4);
        #pragma unroll
        for (int Nt = 0; Nt < 8; ++Nt) acc[Mt][Nt] = c4;
    }
    __syncthreads();

    const int swr = (ln >> 1) & 7;
    const float* dsrc = dhp + bofs4;

    // ---- phase B: {issue dyn float4 loads | MFMA kt0-3 (static) | write dyn}
    #pragma unroll
    for (int hp = 0; hp < 2; ++hp) {
        const int kl = 64 * hp + 16 * w;
        float4v t[8];
        #pragma unroll
        for (int j = 0; j < 8; ++j)
            t[j] = *reinterpret_cast<const float4v*>(dsrc + (size_t)(kl + 8 * hi2 + j) * Nd);
        SFENCE();   // pin load issue above the MFMA cluster

        // MFMA on static chunks: kt = 2hp, 2hp+1 (ckb <= 15)
        #pragma unroll
        for (int kt = 2 * hp; kt < 2 * hp + 2; ++kt) {
            half8 Bf[8];
            const int ckb = kt * 4 + qd;
            #pragma unroll
            for (int Nt = 0; Nt < 8; ++Nt) {
                const int row = Nt * 16 + ln;
                Bf[Nt] = *reinterpret_cast<const half8*>(&xl[row * 256 + ((ckb ^ swr) << 3)]);
            }
            #pragma unroll
            for (int Nt = 0; Nt < 8; ++Nt) {
                acc[0][Nt] = __builtin_amdgcn_mfma_f32_16x16x32_f16(Af[0][kt], Bf[Nt], acc[0][Nt], 0, 0, 0);
                acc[1][Nt] = __builtin_amdgcn_mfma_f32_16x16x32_f16(Af[1][kt], Bf[Nt], acc[1][Nt], 0, 0, 0);
            }
        }
        SFENCE();

        // cvt + swizzled write of the dynamic rows (chunks 16..31)
        const int ck = 16 + (kl >> 3) + hi2;
        #pragma unroll
        for (int r = 0; r < 4; ++r) {
            const int n  = 4 * c31 + r;
            const int sw = (n >> 1) & 7;
            half8 e;
            #pragma unroll
            for (int j = 0; j < 8; ++j) e[j] = (_Float16)t[j][r];
            *reinterpret_cast<half8*>(&xl[n * 256 + ((ck ^ sw) << 3)]) = e;
        }
    }
    __syncthreads();

    // ---- MFMA on dynamic chunks: kt 4..7
    #pragma unroll
    for (int kt = 4; kt < 8; ++kt) {
        half8 Bf[8];
        const int ckb = kt * 4 + qd;
        #pragma unroll
        for (int Nt = 0; Nt < 8; ++Nt) {
            const int row = Nt * 16 + ln;
            Bf[Nt] = *reinterpret_cast<const half8*>(&xl[row * 256 + ((ckb ^ swr) << 3)]);
        }
        #pragma unroll
        for (int Nt = 0; Nt < 8; ++Nt) {
            acc[0][Nt] = __builtin_amdgcn_mfma_f32_16x16x32_f16(Af[0][kt], Bf[Nt], acc[0][Nt], 0, 0, 0);
            acc[1][Nt] = __builtin_amdgcn_mfma_f32_16x16x32_f16(Af[1][kt], Bf[Nt], acc[1][Nt], 0, 0, 0);
        }
    }

    // ---- epilogue: score[n] = sum_m v[m] * tanh(t[m][n])
    float4v v0 = *reinterpret_cast<const float4v*>(v + h0 + qd * 4);
    float4v v1 = *reinterpret_cast<const float4v*>(v + h0 + 16 + qd * 4);
    #pragma unroll
    for (int Nt = 0; Nt < 8; ++Nt) {
        float part = 0.f;
        #pragma unroll
        for (int r = 0; r < 4; ++r) {
            part = fmaf(v0[r], fast_tanh(acc[0][Nt][r]), part);
            part = fmaf(v1[r], fast_tanh(acc[1][Nt][r]), part);
        }
        part += __shfl_xor(part, 16);   // sum quads (same n)
        part += __shfl_xor(part, 32);
        if (qd == 0) red[w * 128 + Nt * 16 + ln] = part;
    }
    __syncthreads();
    if (tid < 128) {
        float s = red[tid] + red[128 + tid] + red[256 + tid] + red[384 + tid];
        out[(size_t)b * Nd + n0 + tid] = s;
    }
}

// ---------------------------------------------------------------------------
// softmax over n=2048 per b, in place. (validated round 1)
__global__ void softmax_k(float* __restrict__ out) {
    int b = blockIdx.x;
    float* row = out + (size_t)b * Nd;
    int tid = threadIdx.x;

    float loc[8];
    float mx = -3.4e38f;
    #pragma unroll
    for (int i = 0; i < 8; ++i) {
        loc[i] = row[tid + (i << 8)];
        mx = fmaxf(mx, loc[i]);
    }
    #pragma unroll
    for (int off = 32; off > 0; off >>= 1) mx = fmaxf(mx, __shfl_xor(mx, off));
    __shared__ float s4[4];
    if ((tid & 63) == 0) s4[tid >> 6] = mx;
    __syncthreads();
    mx = fmaxf(fmaxf(s4[0], s4[1]), fmaxf(s4[2], s4[3]));

    float sum = 0.f;
    #pragma unroll
    for (int i = 0; i < 8; ++i) {
        loc[i] = __expf(loc[i] - mx);
        sum += loc[i];
    }
    #pragma unroll
    for (int off = 32; off > 0; off >>= 1) sum += __shfl_xor(sum, off);
    __shared__ float s4b[4];
    if ((tid & 63) == 0) s4b[tid >> 6] = sum;
    __syncthreads();
    sum = s4b[0] + s4b[1] + s4b[2] + s4b[3];

    float inv = 1.0f / sum;
    #pragma unroll
    for (int i = 0; i < 8; ++i) row[tid + (i << 8)] = loc[i] * inv;
}

// ---------------------------------------------------------------------------
extern "C" void kernel_launch(void* const* d_in, const int* in_sizes, int n_in,
                              void* d_out, int out_size, void* d_ws, size_t ws_size,
                              hipStream_t stream) {
    const float* shp = (const float*)d_in[0];   // static_hidden [B,H,N]
    const float* dhp = (const float*)d_in[1];   // dynamic_hidden [B,H,N]
    const float* dec = (const float*)d_in[2];   // decoder_hidden [B,H]
    const float* v   = (const float*)d_in[3];   // [H]
    const float* W   = (const float*)d_in[4];   // [H, 3H]
    float* out = (float*)d_out;                 // [B,1,N]

    _Float16* Wf = (_Float16*)d_ws;             // 32768 halves = 64 KB
    float* cbp = (float*)((char*)d_ws + 65536); // 32768 floats = 128 KB

    hipLaunchKernelGGL(prep_w16, dim3(128), dim3(256), 0, stream, W, Wf);
    hipLaunchKernelGGL(prep_c,   dim3(Bn),  dim3(Hd),  0, stream, W, dec, cbp);
    hipLaunchKernelGGL(score_kernel, dim3(Nd / 128, Bn), dim3(256), 0, stream,
                       shp, dhp, Wf, cbp, v, out);
    hipLaunchKernelGGL(softmax_k, dim3(Bn), dim3(256), 0, stream, out);
}